// Round 4
// baseline (1663.737 us; speedup 1.0000x reference)
//
#include <hip/hip_runtime.h>

#define NN 8
#define CC 256
#define HH 128
#define WD 128     // width
#define DD 64      // qk dim
#define QKS 132    // padded stride for q/k transposed tiles
#define PTS 136    // padded stride for p-transposed tile

__device__ __forceinline__ float bf2f(unsigned short u){ return __uint_as_float(((unsigned)u)<<16); }
__device__ __forceinline__ unsigned short f2bf(float f){
  unsigned b = __float_as_uint(f);
  return (unsigned short)((b + 0x7FFFu + ((b>>16)&1u)) >> 16);   // RNE, finite inputs
}
__device__ __forceinline__ float bfLo(unsigned u){ return __uint_as_float(u<<16); }
__device__ __forceinline__ float bfHi(unsigned u){ return __uint_as_float(u & 0xFFFF0000u); }
__device__ __forceinline__ float rlane(float v, int l){
  return __int_as_float(__builtin_amdgcn_readlane(__float_as_int(v), l));
}
// order-preserving float->uint key for atomicMax on signed floats
__device__ __forceinline__ unsigned fkey(float f){
  unsigned b = __float_as_uint(f);
  return (b & 0x80000000u) ? ~b : (b | 0x80000000u);
}
__device__ __forceinline__ float funkey(unsigned k){
  return __uint_as_float((k & 0x80000000u) ? (k & 0x7FFFFFFFu) : ~k);
}

__global__ void init_stats(float* __restrict__ sumb, unsigned* __restrict__ maxb){
  int i = blockIdx.x*blockDim.x + threadIdx.x;
  if (i < NN*CC){ sumb[i] = 0.f; maxb[i] = 0u; }
}

// One block per (n,h) row. 256 threads = 4 waves.
__global__ __launch_bounds__(256, 1)
void attn_row_kernel(const float* __restrict__ x, const float* __restrict__ Wq,
                     const float* __restrict__ Wk, const float* __restrict__ Wv,
                     float* __restrict__ outp, float* __restrict__ sumb,
                     unsigned* __restrict__ maxb)
{
  __shared__ unsigned short xs[CC*WD];        // x slab, bf16, [c][i]        64 KiB
  __shared__ unsigned short qk[2*DD*QKS];     // qT[d][i], kT[d][j]          33 KiB
  __shared__ unsigned short pT[WD*PTS];       // p^T [j][i]                  34 KiB

  const int tid  = threadIdx.x;
  const int wave = tid >> 6;
  const int lane = tid & 63;
  const int nb = blockIdx.x >> 7;
  const int h  = blockIdx.x & 127;
  const size_t xbase = (size_t)nb*CC*HH*WD + (size_t)h*WD;   // float offset of x[n,0,h,0]

  // ---------- Phase 1: stage x[n,:,h,:] -> LDS bf16 (float4 coalesced) ----------
  {
    const size_t xb4 = xbase >> 2;
    const float4* xin = (const float4*)x;
    for (int q4 = tid; q4 < CC*(WD/4); q4 += 256){
      int c = q4 >> 5, i4 = q4 & 31;
      float4 f = xin[xb4 + (size_t)c*(HH*WD/4) + i4];
      unsigned* dst = (unsigned*)(xs + c*WD + i4*4);
      dst[0] = (unsigned)f2bf(f.x) | ((unsigned)f2bf(f.y)<<16);
      dst[1] = (unsigned)f2bf(f.z) | ((unsigned)f2bf(f.w)<<16);
    }
  }
  __syncthreads();

  // ---------- Phase 2: q,k projections. thread = (d=lane, i-chunk=wave*32) ----------
  unsigned short* qt = qk;              // qT[d*QKS + i]
  unsigned short* kt = qk + DD*QKS;     // kT[d*QKS + j]
  {
    const int d  = lane;
    const int i0 = wave*32;
    float qa[32], ka[32];
    #pragma unroll
    for (int m=0;m<32;m++){ qa[m]=0.f; ka[m]=0.f; }
    const float* wqr = Wq + d*CC;
    const float* wkr = Wk + d*CC;
    #pragma unroll 2
    for (int c=0;c<CC;c++){
      float wq = wqr[c], wk = wkr[c];
      const uint4* xr = (const uint4*)(xs + c*WD + i0);   // broadcast within wave
      #pragma unroll
      for (int m4=0;m4<4;m4++){
        uint4 u = xr[m4];
        unsigned uu[4] = {u.x,u.y,u.z,u.w};
        #pragma unroll
        for (int e=0;e<4;e++){
          float xl = bfLo(uu[e]), xh = bfHi(uu[e]);
          int m = m4*8 + e*2;
          qa[m] += wq*xl; qa[m+1] += wq*xh;
          ka[m] += wk*xl; ka[m+1] += wk*xh;
        }
      }
    }
    #pragma unroll
    for (int m=0;m<32;m++){
      qt[d*QKS + i0 + m] = f2bf(qa[m]);
      kt[d*QKS + i0 + m] = f2bf(ka[m]);
    }
  }
  __syncthreads();

  // ---------- Phase 3: att rows + wave-parallel softmax -> pT ----------
  // wave owns rows r = wave*32..wave*32+31; lane covers columns (2*lane, 2*lane+1)
  {
    for (int rr=0; rr<32; rr++){
      int r = wave*32 + rr;
      float s0=0.f, s1=0.f;
      #pragma unroll 8
      for (int d=0; d<DD; d++){
        float qv = bf2f(qt[d*QKS + r]);                           // broadcast
        unsigned ku = *(const unsigned*)(kt + d*QKS + 2*lane);    // 2-way free
        s0 += qv*bfLo(ku);
        s1 += qv*bfHi(ku);
      }
      float mx = fmaxf(s0,s1);
      #pragma unroll
      for (int off=32; off; off>>=1) mx = fmaxf(mx, __shfl_xor(mx, off, 64));
      float e0 = __expf(s0-mx), e1 = __expf(s1-mx);
      float sm = e0+e1;
      #pragma unroll
      for (int off=32; off; off>>=1) sm += __shfl_xor(sm, off, 64);
      float inv = 1.0f/sm;
      pT[(2*lane)*PTS   + r] = f2bf(e0*inv);   // p[i=r][j=2*lane]
      pT[(2*lane+1)*PTS + r] = f2bf(e1*inv);
    }
  }
  __syncthreads();

  // ---------- Phase 4: v = Wv*x, out = p @ v^T, fused; 4 channels at a time ----------
  {
    const size_t obase = (size_t)nb*CC*HH*WD + (size_t)h*WD + 2*lane;
    for (int cg=0; cg<16; cg++){
      const int c0 = wave*64 + cg*4;
      float a0l=0,a0h=0,a1l=0,a1h=0,a2l=0,a2h=0,a3l=0,a3h=0;  // v[c][2*lane], v[c][2*lane+1]
      const float* w0 = Wv + (size_t)(c0+0)*CC;
      const float* w1 = Wv + (size_t)(c0+1)*CC;
      const float* w2 = Wv + (size_t)(c0+2)*CC;
      const float* w3 = Wv + (size_t)(c0+3)*CC;
      #pragma unroll 4
      for (int cp=0; cp<CC; cp++){
        unsigned xu = *(const unsigned*)(xs + cp*WD + 2*lane);
        float xl = bfLo(xu), xh = bfHi(xu);
        float f0 = w0[cp], f1 = w1[cp], f2 = w2[cp], f3 = w3[cp];
        a0l += f0*xl; a0h += f0*xh;
        a1l += f1*xl; a1h += f1*xh;
        a2l += f2*xl; a2h += f2*xh;
        a3l += f3*xl; a3h += f3*xh;
      }
      // out[c][i] = sum_j p[i][j] * v[c][j]; i = 2*lane(,+1); v broadcast via readlane
      float o0l=0,o0h=0,o1l=0,o1h=0,o2l=0,o2h=0,o3l=0,o3h=0;
      #pragma unroll 2
      for (int l=0;l<64;l++){
        unsigned u0 = *(const unsigned*)(pT + (2*l)*PTS   + 2*lane); // p[2lane][2l], p[2lane+1][2l]
        unsigned u1 = *(const unsigned*)(pT + (2*l+1)*PTS + 2*lane);
        float pe_l = bfLo(u0), pe_h = bfHi(u0);
        float po_l = bfLo(u1), po_h = bfHi(u1);
        float v0, v1;
        v0 = rlane(a0l, l); v1 = rlane(a0h, l);
        o0l += v0*pe_l + v1*po_l; o0h += v0*pe_h + v1*po_h;
        v0 = rlane(a1l, l); v1 = rlane(a1h, l);
        o1l += v0*pe_l + v1*po_l; o1h += v0*pe_h + v1*po_h;
        v0 = rlane(a2l, l); v1 = rlane(a2h, l);
        o2l += v0*pe_l + v1*po_l; o2h += v0*pe_h + v1*po_h;
        v0 = rlane(a3l, l); v1 = rlane(a3h, l);
        o3l += v0*pe_l + v1*po_l; o3h += v0*pe_h + v1*po_h;
      }
      const float os[4][2] = {{o0l,o0h},{o1l,o1h},{o2l,o2h},{o3l,o3h}};
      #pragma unroll
      for (int t=0;t<4;t++){
        int c = c0+t;
        float2 wv2 = make_float2(os[t][0], os[t][1]);
        *(float2*)(outp + obase + (size_t)c*HH*WD) = wv2;
        float ls = os[t][0] + os[t][1];
        float lm = fmaxf(os[t][0], os[t][1]);
        #pragma unroll
        for (int off=32; off; off>>=1){
          ls += __shfl_xor(ls, off, 64);
          lm = fmaxf(lm, __shfl_xor(lm, off, 64));
        }
        if (lane == 0){
          atomicAdd(sumb + nb*CC + c, ls);
          atomicMax(maxb + nb*CC + c, fkey(lm));
        }
      }
    }
  }
}

// SE gate: one block per n
__global__ void gate_kernel(const float* __restrict__ W1, const float* __restrict__ W2,
                            const float* __restrict__ sumb, const unsigned* __restrict__ maxb,
                            float* __restrict__ gate)
{
  __shared__ float avg_s[CC], max_s[CC], hs[32];
  const int nb = blockIdx.x;
  const int tid = threadIdx.x;
  avg_s[tid] = sumb[nb*CC + tid] * (1.0f/(HH*WD));
  max_s[tid] = funkey(maxb[nb*CC + tid]);
  __syncthreads();
  if (tid < 32){
    int r = tid & 15;
    const float* src = (tid < 16) ? avg_s : max_s;
    const float* w = W1 + r*CC;
    float acc = 0.f;
    for (int c=0;c<CC;c++) acc += src[c]*w[c];
    hs[tid] = fmaxf(acc, 0.f);                 // relu
  }
  __syncthreads();
  float g = 0.f;
  const float* w2r = W2 + tid*16;
  #pragma unroll
  for (int r=0;r<16;r++) g += (hs[r] + hs[16+r]) * w2r[r];
  gate[nb*CC + tid] = 1.0f/(1.0f + __expf(-g));
}

// out = gama * gate[n,c] * out_pre + x  (in-place on d_out)
__global__ void finalize_kernel(const float* __restrict__ x, const float* __restrict__ gate,
                                const float* __restrict__ gama, float* __restrict__ out)
{
  const float g0 = gama[0];
  const long long total4 = (long long)NN*CC*HH*WD/4;
  for (long long i4 = (long long)blockIdx.x*blockDim.x + threadIdx.x; i4 < total4;
       i4 += (long long)gridDim.x*blockDim.x){
    long long flat = i4*4;
    int nc = (int)(flat >> 14);                // (h,w) block = 16384 elems
    float4 ov = ((const float4*)out)[i4];
    float4 xv = ((const float4*)x)[i4];
    float gg = g0 * gate[nc];
    float4 r;
    r.x = gg*ov.x + xv.x;
    r.y = gg*ov.y + xv.y;
    r.z = gg*ov.z + xv.z;
    r.w = gg*ov.w + xv.w;
    ((float4*)out)[i4] = r;
  }
}

extern "C" void kernel_launch(void* const* d_in, const int* in_sizes, int n_in,
                              void* d_out, int out_size, void* d_ws, size_t ws_size,
                              hipStream_t stream)
{
  const float* x    = (const float*)d_in[0];
  const float* Wq   = (const float*)d_in[1];
  const float* Wk   = (const float*)d_in[2];
  const float* Wv   = (const float*)d_in[3];
  const float* W1   = (const float*)d_in[4];
  const float* W2   = (const float*)d_in[5];
  const float* gama = (const float*)d_in[6];
  float* out = (float*)d_out;

  float*    sumb = (float*)d_ws;                 // [2048]
  unsigned* maxb = (unsigned*)d_ws + NN*CC;      // [2048]
  float*    gate = (float*)d_ws + 2*NN*CC;       // [2048]

  hipLaunchKernelGGL(init_stats, dim3(8), dim3(256), 0, stream, sumb, maxb);
  hipLaunchKernelGGL(attn_row_kernel, dim3(NN*HH), dim3(256), 0, stream,
                     x, Wq, Wk, Wv, out, sumb, maxb);
  hipLaunchKernelGGL(gate_kernel, dim3(NN), dim3(256), 0, stream, W1, W2, sumb, maxb, gate);
  hipLaunchKernelGGL(finalize_kernel, dim3(4096), dim3(256), 0, stream, x, gate, gama, out);
}

// Round 5
// 465.728 us; speedup vs baseline: 3.5723x; 3.5723x over previous
//
#include <hip/hip_runtime.h>

#define NN 8
#define CC 256
#define HH 128
#define WD 128     // width (spatial i/j)
#define DD 64      // qk dim

typedef short bf16x8 __attribute__((ext_vector_type(8)));   // 8 bf16 = 4 VGPR
typedef float f32x4 __attribute__((ext_vector_type(4)));

// LDS strides in ushort units
#define XS_STRIDE 256   // xsT[i][c], 16B-block XOR swizzle, no pad (512 B rows)
#define QK_STRIDE 72    // q/k [i|j][d] padded: 144 B rows -> 4-bank row advance
#define P_STRIDE  136   // p[i][j] padded: 272 B rows
#define VT_STRIDE 136   // vtile[c][j]

__device__ __forceinline__ unsigned short f2bf(float f){
  unsigned b = __float_as_uint(f);
  return (unsigned short)((b + 0x7FFFu + ((b>>16)&1u)) >> 16);   // RNE, finite
}
__device__ __forceinline__ unsigned pk2(float a, float b){
  return (unsigned)f2bf(a) | ((unsigned)f2bf(b)<<16);
}
// order-preserving float<->uint key for atomicMax on signed floats
__device__ __forceinline__ unsigned fkey(float f){
  unsigned b = __float_as_uint(f);
  return (b & 0x80000000u) ? ~b : (b | 0x80000000u);
}
__device__ __forceinline__ float funkey(unsigned k){
  return __uint_as_float((k & 0x80000000u) ? (k & 0x7FFFFFFFu) : ~k);
}
// swizzled xsT offset (shorts): row-major, 16B blocks XORed by (row&7)
__device__ __forceinline__ int xs_off(int row, int ccol){
  return row*XS_STRIDE + ((((ccol>>3) ^ (row&7)))<<3);
}

// ---- weights fp32 -> bf16 (ws) + stats init, one launch ----
__global__ void wconv_init(const float* __restrict__ Wq, const float* __restrict__ Wk,
                           const float* __restrict__ Wv,
                           unsigned short* __restrict__ wq, unsigned short* __restrict__ wk,
                           unsigned short* __restrict__ wv,
                           float* __restrict__ sumb, unsigned* __restrict__ maxb){
  int idx = blockIdx.x*256 + threadIdx.x;
  if      (idx < 16384)  wq[idx]        = f2bf(Wq[idx]);
  else if (idx < 32768)  wk[idx-16384]  = f2bf(Wk[idx-16384]);
  else if (idx < 98304)  wv[idx-32768]  = f2bf(Wv[idx-32768]);
  else if (idx < 100352){ int j = idx-98304; sumb[j]=0.f; maxb[j]=0u; }
}

// ---- fused row attention, MFMA bf16. One block per (n,h), 8 waves. ----
// LDS 134 KiB -> 1 block/CU, 8 waves -> 2 waves/SIMD.
__global__ __launch_bounds__(512, 2)
void attn_row_kernel(const float* __restrict__ x,
                     const unsigned short* __restrict__ wqb,
                     const unsigned short* __restrict__ wkb,
                     const unsigned short* __restrict__ wvb,
                     float* __restrict__ outp, float* __restrict__ sumb,
                     unsigned* __restrict__ maxb)
{
  __shared__ unsigned short xsT[128*XS_STRIDE];    // 64 KiB  X^T [i][c] swizzled
  __shared__ unsigned short qk [2*128*QK_STRIDE];  // 36 KiB  q|k ; reused as V dbuf
  __shared__ unsigned short pT [128*P_STRIDE];     // 34 KiB  p  [i][j]

  const int tid  = threadIdx.x;
  const int w    = tid >> 6;        // wave 0..7
  const int lane = tid & 63;
  const int l15  = lane & 15;
  const int qtr  = lane >> 4;       // quarter 0..3
  const int nb = blockIdx.x >> 7;
  const int h  = blockIdx.x & 127;
  const size_t xoff  = (size_t)nb*CC*HH*WD + (size_t)h*WD;

  // ---- Phase 1: transpose-stage x[n,:,h,:] -> xsT[i][c] bf16 (swizzled) ----
  // wave iteration: 8 c-rows (global coalesced float2) -> 2 b128 LDS writes/lane
  #pragma unroll
  for (int it=0; it<4; ++it){
    const int c0 = (w*4 + it)*8;
    float2 v[8];
    #pragma unroll
    for (int r=0;r<8;r++)
      v[r] = *(const float2*)(x + xoff + (size_t)(c0+r)*HH*WD + 2*lane);
    uint4 ra, rb;
    ra.x = pk2(v[0].x,v[1].x); ra.y = pk2(v[2].x,v[3].x);
    ra.z = pk2(v[4].x,v[5].x); ra.w = pk2(v[6].x,v[7].x);
    rb.x = pk2(v[0].y,v[1].y); rb.y = pk2(v[2].y,v[3].y);
    rb.z = pk2(v[4].y,v[5].y); rb.w = pk2(v[6].y,v[7].y);
    const int i0 = 2*lane, i1 = 2*lane+1;
    *(uint4*)(xsT + xs_off(i0, c0)) = ra;
    *(uint4*)(xsT + xs_off(i1, c0)) = rb;
  }
  __syncthreads();

  unsigned short* qlds = qk;
  unsigned short* klds = qk + 128*QK_STRIDE;

  // ---- Phase 2: Q,K projections via MFMA. waves 0-3: Q d-tile w; 4-7: K. ----
  {
    const unsigned short* Wb = (w < 4) ? wqb : wkb;
    unsigned short* dst = (w < 4) ? qlds : klds;
    const int dt = (w & 3);
    f32x4 acc[8];
    #pragma unroll
    for (int i=0;i<8;i++) acc[i] = (f32x4){0.f,0.f,0.f,0.f};
    #pragma unroll
    for (int ks=0; ks<8; ++ks){
      const int ccol = ks*32 + 8*qtr;
      bf16x8 bfrag = *(const bf16x8*)(Wb + (dt*16 + l15)*CC + ccol);  // B[k=c][col=d]
      #pragma unroll
      for (int it=0; it<8; ++it){
        const int row = it*16 + l15;                                   // A row = i
        bf16x8 afrag = *(const bf16x8*)(xsT + xs_off(row, ccol));
        acc[it] = __builtin_amdgcn_mfma_f32_16x16x32_bf16(afrag, bfrag, acc[it], 0,0,0);
      }
    }
    #pragma unroll
    for (int it=0; it<8; ++it)
      #pragma unroll
      for (int r=0; r<4; ++r)   // D: row = 4*qtr+r, col = l15
        dst[(it*16 + 4*qtr + r)*QK_STRIDE + dt*16 + l15] = f2bf(acc[it][r]);
  }
  __syncthreads();

  // ---- Phase 3: S = Q K^T (wave w owns i-tile w), softmax, P -> LDS ----
  {
    f32x4 s[8];
    #pragma unroll
    for (int i=0;i<8;i++) s[i] = (f32x4){0.f,0.f,0.f,0.f};
    #pragma unroll
    for (int jt=0; jt<8; ++jt)
      #pragma unroll
      for (int ks=0; ks<2; ++ks){
        const int dcol = ks*32 + 8*qtr;
        bf16x8 a = *(const bf16x8*)(qlds + (w*16  + l15)*QK_STRIDE + dcol);  // Q[i][d]
        bf16x8 b = *(const bf16x8*)(klds + (jt*16 + l15)*QK_STRIDE + dcol);  // K[j][d]
        s[jt] = __builtin_amdgcn_mfma_f32_16x16x32_bf16(a, b, s[jt], 0,0,0);
      }
    // per-row softmax: row = w*16 + 4*qtr + r lives in this quarter's 16 lanes
    #pragma unroll
    for (int r=0; r<4; ++r){
      float m = s[0][r];
      #pragma unroll
      for (int jt=1; jt<8; ++jt) m = fmaxf(m, s[jt][r]);
      #pragma unroll
      for (int off=1; off<16; off<<=1) m = fmaxf(m, __shfl_xor(m, off, 64));
      float sum = 0.f;
      #pragma unroll
      for (int jt=0; jt<8; ++jt){ float e = __expf(s[jt][r]-m); s[jt][r] = e; sum += e; }
      #pragma unroll
      for (int off=1; off<16; off<<=1) sum += __shfl_xor(sum, off, 64);
      const float inv = 1.0f/sum;
      const int row = w*16 + 4*qtr + r;
      #pragma unroll
      for (int jt=0; jt<8; ++jt)
        pT[row*P_STRIDE + jt*16 + l15] = f2bf(s[jt][r]*inv);
    }
  }
  __syncthreads();

  // ---- Phase 4: per 64-channel tile: V = Wv X (MFMA) -> LDS, then O = V P^T ----
  const int wv = w >> 1;            // c-subtile 0..3 within the 64-c tile
  const int ng = (w & 1)*4;         // 4 of 8 spatial tiles
  #pragma unroll 1
  for (int t=0; t<4; ++t){
    unsigned short* vt = qk + (t&1)*(64*VT_STRIDE);   // double buffer in q/k space
    const int cbase = t*64;
    // V-tile: M=c(16 rows), N=j
    f32x4 vacc[4];
    #pragma unroll
    for (int i=0;i<4;i++) vacc[i] = (f32x4){0.f,0.f,0.f,0.f};
    #pragma unroll
    for (int ks=0; ks<8; ++ks){
      const int ccol = ks*32 + 8*qtr;
      bf16x8 a = *(const bf16x8*)(wvb + (size_t)(cbase + wv*16 + l15)*CC + ccol); // Wv[c][cp]
      #pragma unroll
      for (int nn=0; nn<4; ++nn){
        const int jrow = (ng+nn)*16 + l15;
        bf16x8 b = *(const bf16x8*)(xsT + xs_off(jrow, ccol));                    // X[cp][j]
        vacc[nn] = __builtin_amdgcn_mfma_f32_16x16x32_bf16(a, b, vacc[nn], 0,0,0);
      }
    }
    #pragma unroll
    for (int nn=0; nn<4; ++nn)
      #pragma unroll
      for (int r=0; r<4; ++r)
        vt[(wv*16 + 4*qtr + r)*VT_STRIDE + (ng+nn)*16 + l15] = f2bf(vacc[nn][r]);
    __syncthreads();
    // PV: M=c, N=i, K=j
    f32x4 oacc[4];
    #pragma unroll
    for (int i=0;i<4;i++) oacc[i] = (f32x4){0.f,0.f,0.f,0.f};
    #pragma unroll
    for (int ks=0; ks<4; ++ks){
      const int jcol = ks*32 + 8*qtr;
      bf16x8 a = *(const bf16x8*)(vt + (wv*16 + l15)*VT_STRIDE + jcol);           // V[c][j]
      #pragma unroll
      for (int nn=0; nn<4; ++nn){
        bf16x8 b = *(const bf16x8*)(pT + ((ng+nn)*16 + l15)*P_STRIDE + jcol);     // P[i][j]
        oacc[nn] = __builtin_amdgcn_mfma_f32_16x16x32_bf16(a, b, oacc[nn], 0,0,0);
      }
    }
    // write out (16 consecutive i per quarter) + SE partials
    #pragma unroll
    for (int nn=0; nn<4; ++nn){
      const int i_abs = (ng+nn)*16 + l15;
      #pragma unroll
      for (int r=0; r<4; ++r){
        const int c_abs = cbase + wv*16 + 4*qtr + r;
        outp[(size_t)nb*CC*HH*WD + (size_t)c_abs*HH*WD + (size_t)h*WD + i_abs] = oacc[nn][r];
      }
    }
    #pragma unroll
    for (int r=0; r<4; ++r){
      float ssum = oacc[0][r]+oacc[1][r]+oacc[2][r]+oacc[3][r];
      float smax = fmaxf(fmaxf(oacc[0][r],oacc[1][r]), fmaxf(oacc[2][r],oacc[3][r]));
      #pragma unroll
      for (int off=1; off<16; off<<=1){
        ssum += __shfl_xor(ssum, off, 64);
        smax  = fmaxf(smax, __shfl_xor(smax, off, 64));
      }
      if (l15 == 0){
        const int c_abs = cbase + wv*16 + 4*qtr + r;
        atomicAdd(sumb + nb*CC + c_abs, ssum);
        atomicMax(maxb + nb*CC + c_abs, fkey(smax));
      }
    }
  }
}

// ---- SE gate: one block per n ----
__global__ void gate_kernel(const float* __restrict__ W1, const float* __restrict__ W2,
                            const float* __restrict__ sumb, const unsigned* __restrict__ maxb,
                            float* __restrict__ gate)
{
  __shared__ float avg_s[CC], max_s[CC], hs[32];
  const int nb = blockIdx.x;
  const int tid = threadIdx.x;
  avg_s[tid] = sumb[nb*CC + tid] * (1.0f/(HH*WD));
  max_s[tid] = funkey(maxb[nb*CC + tid]);
  __syncthreads();
  if (tid < 32){
    int r = tid & 15;
    const float* src = (tid < 16) ? avg_s : max_s;
    const float* wr = W1 + r*CC;
    float acc = 0.f;
    for (int c=0;c<CC;c++) acc += src[c]*wr[c];
    hs[tid] = fmaxf(acc, 0.f);
  }
  __syncthreads();
  float g = 0.f;
  const float* w2r = W2 + tid*16;
  #pragma unroll
  for (int r=0;r<16;r++) g += (hs[r] + hs[16+r]) * w2r[r];
  gate[nb*CC + tid] = 1.0f/(1.0f + __expf(-g));
}

// ---- out = gama * gate[n,c] * out_pre + x (in-place on d_out) ----
__global__ void finalize_kernel(const float* __restrict__ x, const float* __restrict__ gate,
                                const float* __restrict__ gama, float* __restrict__ out)
{
  const float g0 = gama[0];
  const long long total4 = (long long)NN*CC*HH*WD/4;
  for (long long i4 = (long long)blockIdx.x*blockDim.x + threadIdx.x; i4 < total4;
       i4 += (long long)gridDim.x*blockDim.x){
    long long flat = i4*4;
    int nc = (int)(flat >> 14);
    float4 ov = ((const float4*)out)[i4];
    float4 xv = ((const float4*)x)[i4];
    float gg = g0 * gate[nc];
    float4 r;
    r.x = gg*ov.x + xv.x;
    r.y = gg*ov.y + xv.y;
    r.z = gg*ov.z + xv.z;
    r.w = gg*ov.w + xv.w;
    ((float4*)out)[i4] = r;
  }
}

extern "C" void kernel_launch(void* const* d_in, const int* in_sizes, int n_in,
                              void* d_out, int out_size, void* d_ws, size_t ws_size,
                              hipStream_t stream)
{
  const float* x    = (const float*)d_in[0];
  const float* Wq   = (const float*)d_in[1];
  const float* Wk   = (const float*)d_in[2];
  const float* Wv   = (const float*)d_in[3];
  const float* W1   = (const float*)d_in[4];
  const float* W2   = (const float*)d_in[5];
  const float* gama = (const float*)d_in[6];
  float* out = (float*)d_out;

  // ws layout (bytes): wq 32768 | wk 32768 | wv 131072 | sumb 8192 | maxb 8192 | gate 8192
  unsigned short* wq_bf = (unsigned short*)d_ws;
  unsigned short* wk_bf = wq_bf + 64*CC;
  unsigned short* wv_bf = wk_bf + 64*CC;
  float*    sumb = (float*)((char*)d_ws + 196608);
  unsigned* maxb = (unsigned*)((char*)d_ws + 204800);
  float*    gate = (float*)((char*)d_ws + 212992);

  hipLaunchKernelGGL(wconv_init, dim3(392), dim3(256), 0, stream,
                     Wq, Wk, Wv, wq_bf, wk_bf, wv_bf, sumb, maxb);
  hipLaunchKernelGGL(attn_row_kernel, dim3(NN*HH), dim3(512), 0, stream,
                     x, wq_bf, wk_bf, wv_bf, out, sumb, maxb);
  hipLaunchKernelGGL(gate_kernel, dim3(NN), dim3(256), 0, stream, W1, W2, sumb, maxb, gate);
  hipLaunchKernelGGL(finalize_kernel, dim3(4096), dim3(256), 0, stream, x, gate, gama, out);
}

// Round 6
// 375.711 us; speedup vs baseline: 4.4282x; 1.2396x over previous
//
#include <hip/hip_runtime.h>

#define NN 8
#define CC 256
#define HH 128
#define WD 128
#define DD 64
#define XP_S 40   // xp row stride in shorts (80 B): conflict-free b128 row reads

typedef short bf16x8 __attribute__((ext_vector_type(8)));
typedef float f32x4 __attribute__((ext_vector_type(4)));

__device__ __forceinline__ unsigned short f2bf(float f){
  unsigned b = __float_as_uint(f);
  return (unsigned short)((b + 0x7FFFu + ((b>>16)&1u)) >> 16);   // RNE, finite
}
__device__ __forceinline__ unsigned pk2(float a, float b){
  return (unsigned)f2bf(a) | ((unsigned)f2bf(b)<<16);
}
__device__ __forceinline__ unsigned fkey(float f){
  unsigned b = __float_as_uint(f);
  return (b & 0x80000000u) ? ~b : (b | 0x80000000u);
}
__device__ __forceinline__ float funkey(unsigned k){
  return __uint_as_float((k & 0x80000000u) ? (k & 0x7FFFFFFFu) : ~k);
}
// qz: [128][64] rows, 8x16B blocks XOR-swizzled by row&7
__device__ __forceinline__ int off64(int row, int col){
  return (row<<6) + ((((col>>3) ^ (row&7))<<3) | (col&7));
}
// pz/vt: [128][128] rows, 16x16B blocks XOR-swizzled by row&15
__device__ __forceinline__ int off128(int row, int col){
  return (row<<7) + ((((col>>3) ^ (row&15))<<3) | (col&7));
}

__global__ void wconv_init(const float* __restrict__ Wq, const float* __restrict__ Wk,
                           const float* __restrict__ Wv,
                           unsigned short* __restrict__ wq, unsigned short* __restrict__ wk,
                           unsigned short* __restrict__ wv,
                           float* __restrict__ sumb, unsigned* __restrict__ maxb){
  int idx = blockIdx.x*256 + threadIdx.x;
  if      (idx < 16384)  wq[idx]        = f2bf(Wq[idx]);
  else if (idx < 32768)  wk[idx-16384]  = f2bf(Wk[idx-16384]);
  else if (idx < 98304)  wv[idx-32768]  = f2bf(Wv[idx-32768]);
  else if (idx < 100352){ int j = idx-98304; sumb[j]=0.f; maxb[j]=0u; }
}

// One block per (n,h). 8 waves, 74 KiB LDS -> 2 blocks/CU (4 waves/SIMD).
__global__ __launch_bounds__(512, 4)
void attn_row_kernel(const float* __restrict__ x,
                     const unsigned short* __restrict__ wqb,
                     const unsigned short* __restrict__ wkb,
                     const unsigned short* __restrict__ wvb,
                     float* __restrict__ outp, float* __restrict__ sumb,
                     unsigned* __restrict__ maxb)
{
  __shared__ unsigned short xp[128*XP_S];   // 10 KiB  X^T panel [i][32c], pad-40
  __shared__ unsigned short qz[2*128*64];   // 32 KiB  Q|K [i][d] swz; reused as V [c][j]
  __shared__ unsigned short pz[128*128];    // 32 KiB  P [i][j] swz

  const int tid  = threadIdx.x;
  const int w    = tid >> 6;
  const int lane = tid & 63;
  const int l15  = lane & 15;
  const int qtr  = lane >> 4;
  const int nb   = blockIdx.x >> 7;
  const int hrow = blockIdx.x & 127;
  const size_t xoff = (size_t)nb*CC*HH*WD + (size_t)hrow*WD;

  // wave w stages panel c-rows 4w..4w+3; lane covers i = 2*lane, 2*lane+1
#define LOADP(P, V)                                                               \
  { _Pragma("unroll")                                                             \
    for (int r=0;r<4;r++)                                                         \
      V[r] = *(const float2*)(x + xoff + (size_t)((P)*32 + 4*w + r)*HH*WD + 2*lane); }
#define WRITEP(V)                                                                 \
  { uint2 ua, ub;                                                                 \
    ua.x = pk2(V[0].x, V[1].x); ua.y = pk2(V[2].x, V[3].x);                       \
    ub.x = pk2(V[0].y, V[1].y); ub.y = pk2(V[2].y, V[3].y);                       \
    *(uint2*)(xp + (2*lane)*XP_S + 4*w)   = ua;                                   \
    *(uint2*)(xp + (2*lane+1)*XP_S + 4*w) = ub; }

  float2 pv[4], nv[4];

  // ---- Phase A: stream panels, accumulate Q (waves 0-3) / K (waves 4-7) ----
  LOADP(0, pv);
  WRITEP(pv);
  __syncthreads();
  const unsigned short* Wb = (w < 4) ? wqb : wkb;
  const int dt = w & 3;
  f32x4 qk[8];
  #pragma unroll
  for (int i=0;i<8;i++) qk[i] = (f32x4){0.f,0.f,0.f,0.f};
  for (int p=0; p<8; ++p){
    if (p<7) LOADP(p+1, nv);
    bf16x8 bq = *(const bf16x8*)(Wb + (dt*16 + l15)*CC + p*32 + 8*qtr);
    #pragma unroll
    for (int it=0; it<8; ++it){
      bf16x8 a = *(const bf16x8*)(xp + (it*16 + l15)*XP_S + 8*qtr);
      qk[it] = __builtin_amdgcn_mfma_f32_16x16x32_bf16(a, bq, qk[it], 0,0,0);
    }
    __syncthreads();
    if (p<7){ WRITEP(nv); __syncthreads(); }
  }
  {  // dump Q/K -> qz (swizzled): row=i, col=d
    unsigned short* dst = qz + ((w<4) ? 0 : 8192);
    #pragma unroll
    for (int it=0; it<8; ++it)
      #pragma unroll
      for (int r=0; r<4; ++r)
        dst[off64(it*16 + 4*qtr + r, dt*16 + l15)] = f2bf(qk[it][r]);
  }
  LOADP(0, pv);           // prefetch phase-C panel 0 across phase B
  __syncthreads();

  // ---- Phase B: S = Q K^T (wave w owns i-tile w), softmax, P -> pz ----
  {
    f32x4 s[8];
    #pragma unroll
    for (int i=0;i<8;i++) s[i] = (f32x4){0.f,0.f,0.f,0.f};
    #pragma unroll
    for (int jt=0; jt<8; ++jt)
      #pragma unroll
      for (int ks=0; ks<2; ++ks){
        const int dcol = ks*32 + 8*qtr;
        bf16x8 a = *(const bf16x8*)(qz + off64(w*16 + l15, dcol));
        bf16x8 b = *(const bf16x8*)(qz + 8192 + off64(jt*16 + l15, dcol));
        s[jt] = __builtin_amdgcn_mfma_f32_16x16x32_bf16(a, b, s[jt], 0,0,0);
      }
    #pragma unroll
    for (int r=0; r<4; ++r){
      float m = s[0][r];
      #pragma unroll
      for (int jt=1; jt<8; ++jt) m = fmaxf(m, s[jt][r]);
      #pragma unroll
      for (int off=1; off<16; off<<=1) m = fmaxf(m, __shfl_xor(m, off, 64));
      float sum = 0.f;
      #pragma unroll
      for (int jt=0; jt<8; ++jt){ float e = __expf(s[jt][r]-m); s[jt][r]=e; sum += e; }
      #pragma unroll
      for (int off=1; off<16; off<<=1) sum += __shfl_xor(sum, off, 64);
      const float inv = 1.0f/sum;
      const int row = w*16 + 4*qtr + r;
      #pragma unroll
      for (int jt=0; jt<8; ++jt)
        pz[off128(row, jt*16 + l15)] = f2bf(s[jt][r]*inv);
    }
  }
  __syncthreads();

  // ---- Phase C: stream panels again, V = Wv·X in registers (2 c-tiles/wave) ----
  WRITEP(pv);
  __syncthreads();
  f32x4 v0[8], v1[8];
  #pragma unroll
  for (int i=0;i<8;i++){ v0[i] = (f32x4){0.f,0.f,0.f,0.f}; v1[i] = v0[i]; }
  for (int p=0; p<8; ++p){
    if (p<7) LOADP(p+1, nv);
    bf16x8 a0 = *(const bf16x8*)(wvb + (size_t)(16*w + l15)*CC       + p*32 + 8*qtr);
    bf16x8 a1 = *(const bf16x8*)(wvb + (size_t)(128 + 16*w + l15)*CC + p*32 + 8*qtr);
    #pragma unroll
    for (int jt=0; jt<8; ++jt){
      bf16x8 b = *(const bf16x8*)(xp + (jt*16 + l15)*XP_S + 8*qtr);
      v0[jt] = __builtin_amdgcn_mfma_f32_16x16x32_bf16(a0, b, v0[jt], 0,0,0);
      v1[jt] = __builtin_amdgcn_mfma_f32_16x16x32_bf16(a1, b, v1[jt], 0,0,0);
    }
    __syncthreads();
    if (p<7){ WRITEP(nv); __syncthreads(); }
  }

  // ---- Phase D: two 128-c halves: dump V -> vt (qz region), O = V·P^T ----
  unsigned short* vt = qz;
  for (int hf=0; hf<2; ++hf){
    #pragma unroll
    for (int jt=0; jt<8; ++jt)
      #pragma unroll
      for (int r=0; r<4; ++r){
        float vv = hf ? v1[jt][r] : v0[jt][r];
        vt[off128(16*w + 4*qtr + r, jt*16 + l15)] = f2bf(vv);
      }
    __syncthreads();
    f32x4 oa[8];
    #pragma unroll
    for (int i=0;i<8;i++) oa[i] = (f32x4){0.f,0.f,0.f,0.f};
    #pragma unroll
    for (int ks=0; ks<4; ++ks){
      const int jcol = ks*32 + 8*qtr;
      bf16x8 a = *(const bf16x8*)(vt + off128(16*w + l15, jcol));
      #pragma unroll
      for (int it=0; it<8; ++it){
        bf16x8 b = *(const bf16x8*)(pz + off128(16*it + l15, jcol));
        oa[it] = __builtin_amdgcn_mfma_f32_16x16x32_bf16(a, b, oa[it], 0,0,0);
      }
    }
    #pragma unroll
    for (int it=0; it<8; ++it)
      #pragma unroll
      for (int r=0; r<4; ++r){
        const int c_abs = 128*hf + 16*w + 4*qtr + r;
        outp[(size_t)nb*CC*HH*WD + (size_t)c_abs*HH*WD + (size_t)hrow*WD + 16*it + l15] = oa[it][r];
      }
    #pragma unroll
    for (int r=0; r<4; ++r){
      float ssum = 0.f, smax = -3.4e38f;
      #pragma unroll
      for (int it=0; it<8; ++it){ ssum += oa[it][r]; smax = fmaxf(smax, oa[it][r]); }
      #pragma unroll
      for (int off=1; off<16; off<<=1){
        ssum += __shfl_xor(ssum, off, 64);
        smax  = fmaxf(smax, __shfl_xor(smax, off, 64));
      }
      if (l15 == 0){
        const int c_abs = 128*hf + 16*w + 4*qtr + r;
        atomicAdd(sumb + nb*CC + c_abs, ssum);
        atomicMax(maxb + nb*CC + c_abs, fkey(smax));
      }
    }
    __syncthreads();
  }
#undef LOADP
#undef WRITEP
}

// ---- SE gate: one block per n ----
__global__ void gate_kernel(const float* __restrict__ W1, const float* __restrict__ W2,
                            const float* __restrict__ sumb, const unsigned* __restrict__ maxb,
                            float* __restrict__ gate)
{
  __shared__ float avg_s[CC], max_s[CC], hs[32];
  const int nb = blockIdx.x;
  const int tid = threadIdx.x;
  avg_s[tid] = sumb[nb*CC + tid] * (1.0f/(HH*WD));
  max_s[tid] = funkey(maxb[nb*CC + tid]);
  __syncthreads();
  if (tid < 32){
    int r = tid & 15;
    const float* src = (tid < 16) ? avg_s : max_s;
    const float* wr = W1 + r*CC;
    float acc = 0.f;
    for (int c=0;c<CC;c++) acc += src[c]*wr[c];
    hs[tid] = fmaxf(acc, 0.f);
  }
  __syncthreads();
  float g = 0.f;
  const float* w2r = W2 + tid*16;
  #pragma unroll
  for (int r=0;r<16;r++) g += (hs[r] + hs[16+r]) * w2r[r];
  gate[nb*CC + tid] = 1.0f/(1.0f + __expf(-g));
}

// ---- out = gama * gate[n,c] * out_pre + x (in-place on d_out) ----
__global__ void finalize_kernel(const float* __restrict__ x, const float* __restrict__ gate,
                                const float* __restrict__ gama, float* __restrict__ out)
{
  const float g0 = gama[0];
  const long long total4 = (long long)NN*CC*HH*WD/4;
  for (long long i4 = (long long)blockIdx.x*blockDim.x + threadIdx.x; i4 < total4;
       i4 += (long long)gridDim.x*blockDim.x){
    long long flat = i4*4;
    int nc = (int)(flat >> 14);
    float4 ov = ((const float4*)out)[i4];
    float4 xv = ((const float4*)x)[i4];
    float gg = g0 * gate[nc];
    float4 r;
    r.x = gg*ov.x + xv.x;
    r.y = gg*ov.y + xv.y;
    r.z = gg*ov.z + xv.z;
    r.w = gg*ov.w + xv.w;
    ((float4*)out)[i4] = r;
  }
}

extern "C" void kernel_launch(void* const* d_in, const int* in_sizes, int n_in,
                              void* d_out, int out_size, void* d_ws, size_t ws_size,
                              hipStream_t stream)
{
  const float* x    = (const float*)d_in[0];
  const float* Wq   = (const float*)d_in[1];
  const float* Wk   = (const float*)d_in[2];
  const float* Wv   = (const float*)d_in[3];
  const float* W1   = (const float*)d_in[4];
  const float* W2   = (const float*)d_in[5];
  const float* gama = (const float*)d_in[6];
  float* out = (float*)d_out;

  unsigned short* wq_bf = (unsigned short*)d_ws;
  unsigned short* wk_bf = wq_bf + 64*CC;
  unsigned short* wv_bf = wk_bf + 64*CC;
  float*    sumb = (float*)((char*)d_ws + 196608);
  unsigned* maxb = (unsigned*)((char*)d_ws + 204800);
  float*    gate = (float*)((char*)d_ws + 212992);

  hipLaunchKernelGGL(wconv_init, dim3(392), dim3(256), 0, stream,
                     Wq, Wk, Wv, wq_bf, wk_bf, wv_bf, sumb, maxb);
  hipLaunchKernelGGL(attn_row_kernel, dim3(NN*HH), dim3(512), 0, stream,
                     x, wq_bf, wk_bf, wv_bf, out, sumb, maxb);
  hipLaunchKernelGGL(gate_kernel, dim3(NN), dim3(256), 0, stream, W1, W2, sumb, maxb, gate);
  hipLaunchKernelGGL(finalize_kernel, dim3(4096), dim3(256), 0, stream, x, gate, gama, out);
}